// Round 6
// baseline (604.184 us; speedup 1.0000x reference)
//
#include <hip/hip_runtime.h>

// LSTM B=4096, T=2048, H=15.  R5: 32 lanes/element, 2 waves/SIMD, all
// cross-lane on the VALU pipe (DPP row_ror + v_permlane32_swap), zero LDS.
//   element A: lanes 0-15 (half0: gate rows i,f) + lanes 32-47 (half1: g,o)
//   element B: lanes 16-31 (half0)               + lanes 48-63 (half1)
// Half-exchange of activated gates = ONE v_permlane32_swap (lower/upper
// 32-lane broadcast pair), ~4cy vs R1-R3's ds_swizzle ~120cy.
// Both gate rows accumulate in one packed (v_pk_fma_f32) dual-accum chain.
// h all-gather: 15x DPP row_ror within each 16-lane row, weights pre-rotated
// at init (self-calibrated by pushing lane index through the same DPP ops).
// R4 lesson: 1 wave/SIMD exposed ~180cy/step of chain stall; 2 waves/SIMD
// cover it and packed gates halve issue.

#define HID 15
#define T_LEN 2048
#define B_TOT 4096

typedef float v2f __attribute__((ext_vector_type(2)));

__device__ __forceinline__ v2f fma2(v2f a, v2f b, v2f c) {
    return __builtin_elementwise_fma(a, b, c);
}

template<int CTRL>
__device__ __forceinline__ int dpp_i(int v) {
    return __builtin_amdgcn_update_dpp(0, v, CTRL, 0xF, 0xF, true);
}
template<int CTRL>
__device__ __forceinline__ float dpp_f(float v) {
    return __int_as_float(
        __builtin_amdgcn_update_dpp(0, __float_as_int(v), CTRL, 0xF, 0xF, true));
}

__global__ __launch_bounds__(256) __attribute__((amdgpu_waves_per_eu(2, 2)))
void lstm_seq_kernel(
    const float* __restrict__ x,      // (B, T)
    const float* __restrict__ W_ih,   // (60, 1)
    const float* __restrict__ W_hh,   // (60, 15)
    const float* __restrict__ b_ih,   // (60,)
    const float* __restrict__ b_hh,   // (60,)
    const float* __restrict__ W_lin,  // (1, 15)
    const float* __restrict__ b_lin,  // (1,)
    float* __restrict__ out)          // (B, T)
{
    const int tid  = threadIdx.x;
    const int lane = tid & 63;
    const int sub  = tid & 15;                       // unit slot in 16-row
    const int eidx = (tid >> 4) & 1;                 // element within wave
    const int hf   = (tid >> 5) & 1;                 // 0: rows i,f  1: rows g,o
    const int u    = (sub < HID) ? sub : (HID - 1);  // lane 15 dups unit 14
    const int b    = blockIdx.x * 8 + (tid >> 6) * 2 + eidx;

    // ---- self-calibrate the row_ror permutation (direction-proof) ----
    int pos[16];
    pos[0]  = sub;
    pos[1]  = dpp_i<0x121>(sub);  pos[2]  = dpp_i<0x122>(sub);
    pos[3]  = dpp_i<0x123>(sub);  pos[4]  = dpp_i<0x124>(sub);
    pos[5]  = dpp_i<0x125>(sub);  pos[6]  = dpp_i<0x126>(sub);
    pos[7]  = dpp_i<0x127>(sub);  pos[8]  = dpp_i<0x128>(sub);
    pos[9]  = dpp_i<0x129>(sub);  pos[10] = dpp_i<0x12A>(sub);
    pos[11] = dpp_i<0x12B>(sub);  pos[12] = dpp_i<0x12C>(sub);
    pos[13] = dpp_i<0x12D>(sub);  pos[14] = dpp_i<0x12E>(sub);
    pos[15] = dpp_i<0x12F>(sub);

    // ---- self-calibrate permlane32_swap return order ----
    // swap(v,v) returns {lower-half-bcast, upper-half-bcast} in SOME order;
    // detect which by pushing the lane id through.
    auto cal = __builtin_amdgcn_permlane32_swap((unsigned)lane, (unsigned)lane,
                                                false, false);
    const bool xlo = ((__builtin_amdgcn_readfirstlane((int)cal[0]) & 32) == 0);

    // ---- packed, pre-rotated weights: wp[j] = {W_hh[row0][p], W_hh[row1][p]}
    const int row0 = hf * 2 * HID + u;     // i-row (half0) or g-row (half1)
    const int row1 = row0 + HID;           // f-row (half0) or o-row (half1)
    v2f wp[16];
#pragma unroll
    for (int j = 0; j < 16; ++j) {
        const int p = pos[j];
        const bool v = (p < HID);
        wp[j].x = v ? W_hh[row0 * HID + p] : 0.0f;
        wp[j].y = v ? W_hh[row1 * HID + p] : 0.0f;
    }
    v2f wih; wih.x = W_ih[row0]; wih.y = W_ih[row1];
    v2f bia; bia.x = b_ih[row0] + b_hh[row0]; bia.y = b_ih[row1] + b_hh[row1];
    const float wlin_m = (sub < HID) ? W_lin[sub] : 0.0f;   // lane15 masked
    const float blin = b_lin[0];

    const float L = 1.44269504088896341f;  // log2(e)
    // gate0 activation: sigmoid (half0: i) | tanh (half1: g); gate1 sigmoid
    const float m0 = hf ? 2.0f : 1.0f;
    const float d0 = hf ? -1.0f : 0.0f;
    v2f sv; sv.x = hf ? (-2.0f * L) : (-L); sv.y = -L;

    float c = 0.0f, hl = 0.0f;
    float hr[16];
#pragma unroll
    for (int j = 0; j < 16; ++j) hr[j] = 0.0f;

    const float4* __restrict__ x4 = (const float4*)(x + (size_t)b * T_LEN);
    float4* __restrict__ o4       = (float4*)(out + (size_t)b * T_LEN);

    float4 xv = x4[0];
    for (int t0 = 0; t0 < T_LEN / 4; ++t0) {
        const int tn = (t0 + 1 < T_LEN / 4) ? (t0 + 1) : t0;
        const float4 xnext = x4[tn];       // prefetch; hides under 4 steps
        float ov[4];
#pragma unroll
        for (int s = 0; s < 4; ++s) {
            const float xt = (s == 0) ? xv.x : (s == 1) ? xv.y : (s == 2) ? xv.z : xv.w;

            // ---- both gate rows: one packed dual-accumulator chain ----
            v2f ae = bia;
            v2f ao; ao.x = 0.0f; ao.y = 0.0f;
#pragma unroll
            for (int j = 0; j < 16; j += 2) {
                ae = fma2((v2f){hr[j],     hr[j]},     wp[j],     ae);
                ao = fma2((v2f){hr[j + 1], hr[j + 1]}, wp[j + 1], ao);
            }
            const v2f g = fma2((v2f){xt, xt}, wih, ae + ao);

            // ---- activations: a0 = sig(i)|tanh(g), a1 = sig(f)|sig(o) ----
            const v2f earg = g * sv;
            const float e0 = __builtin_amdgcn_exp2f(earg.x);
            const float e1 = __builtin_amdgcn_exp2f(earg.y);
            const float r0 = __builtin_amdgcn_rcpf(1.0f + e0);
            const float a1 = __builtin_amdgcn_rcpf(1.0f + e1);
            const float a0 = fmaf(m0, r0, d0);

            // ---- half-exchange via permlane32_swap (VALU, ~4cy) ----
            auto ra = __builtin_amdgcn_permlane32_swap(
                (unsigned)__float_as_int(a0), (unsigned)__float_as_int(a0),
                false, false);
            auto rb = __builtin_amdgcn_permlane32_swap(
                (unsigned)__float_as_int(a1), (unsigned)__float_as_int(a1),
                false, false);
            // ra parts are {si, tg} in calibration-dependent order; product
            // si*tg is commutative -> no select needed.
            const float prod = __int_as_float((int)ra[0]) * __int_as_float((int)ra[1]);
            const float rbx = __int_as_float((int)rb[0]);
            const float rby = __int_as_float((int)rb[1]);
            const float sfv = xlo ? rbx : rby;     // sigmoid(f) (lower half a1)
            const float sov = xlo ? rby : rbx;     // sigmoid(o) (upper half a1)

            // ---- cell update (identical on both halves) ----
            c = fmaf(sfv, c, prod);
            const float tc = fmaf(2.0f,
                __builtin_amdgcn_rcpf(1.0f + __builtin_amdgcn_exp2f(c * (-2.0f * L))),
                -1.0f);
            hl = sov * tc;

            // ---- out-projection: DPP butterfly within the 16-row ----
            float p = hl * wlin_m;
            p += dpp_f<0x0B1>(p);   // quad_perm xor1
            p += dpp_f<0x04E>(p);   // quad_perm xor2
            p += dpp_f<0x140>(p);   // row_mirror
            p += dpp_f<0x141>(p);   // half_mirror
            ov[s] = p + blin;

            // ---- h all-gather for next step (independent of projection) ----
            hr[0]  = hl;
            hr[1]  = dpp_f<0x121>(hl);  hr[2]  = dpp_f<0x122>(hl);
            hr[3]  = dpp_f<0x123>(hl);  hr[4]  = dpp_f<0x124>(hl);
            hr[5]  = dpp_f<0x125>(hl);  hr[6]  = dpp_f<0x126>(hl);
            hr[7]  = dpp_f<0x127>(hl);  hr[8]  = dpp_f<0x128>(hl);
            hr[9]  = dpp_f<0x129>(hl);  hr[10] = dpp_f<0x12A>(hl);
            hr[11] = dpp_f<0x12B>(hl);  hr[12] = dpp_f<0x12C>(hl);
            hr[13] = dpp_f<0x12D>(hl);  hr[14] = dpp_f<0x12E>(hl);
            hr[15] = dpp_f<0x12F>(hl);
        }
        if (sub == 0 && hf == 0) {
            o4[t0] = make_float4(ov[0], ov[1], ov[2], ov[3]);
        }
        xv = xnext;
    }
}

extern "C" void kernel_launch(void* const* d_in, const int* in_sizes, int n_in,
                              void* d_out, int out_size, void* d_ws, size_t ws_size,
                              hipStream_t stream) {
    const float* x     = (const float*)d_in[0];
    const float* W_ih  = (const float*)d_in[1];
    const float* W_hh  = (const float*)d_in[2];
    const float* b_ih  = (const float*)d_in[3];
    const float* b_hh  = (const float*)d_in[4];
    const float* W_lin = (const float*)d_in[5];
    const float* b_lin = (const float*)d_in[6];
    float* out = (float*)d_out;

    dim3 grid(B_TOT / 8);    // 512 blocks, 8 elements each
    dim3 block(256);         // 4 waves/block, 2 elements/wave -> 2 waves/SIMD
    lstm_seq_kernel<<<grid, block, 0, stream>>>(x, W_ih, W_hh, b_ih, b_hh,
                                                W_lin, b_lin, out);
}

// Round 7
// 455.847 us; speedup vs baseline: 1.3254x; 1.3254x over previous
//
#include <hip/hip_runtime.h>

// LSTM B=4096, T=2048, H=15.  R6 = R4 structure (best so far, 538us rocprof)
// + packed gate chains.
// 16 lanes per batch element; lane u owns unit u and computes ALL 4 of its
// gates -> cell update fully lane-local, no gate exchange, zero LDS.
// h all-gather: 15x v_mov_b32_dpp row_ror:j, weights PRE-ROTATED at init
// (self-calibrated by pushing lane index through the same DPP ops).
// Gate math: 2x v_pk_fma_f32 dual-accumulator chains ({i,f} and {g,o}) =
// 32 packed FMA vs R4's 64 scalar FMA (the largest issue term, -64cy/step).
// Output projection: DPP butterfly (involutions, direction-proof).
// R5 lesson: per-wave fixed overhead is paid per wave, not per element ->
// keep 4 elements/wave; do NOT trade elements/wave for occupancy.

#define HID 15
#define T_LEN 2048
#define B_TOT 4096

typedef float v2f __attribute__((ext_vector_type(2)));

__device__ __forceinline__ v2f fma2(v2f a, v2f b, v2f c) {
    return __builtin_elementwise_fma(a, b, c);
}

template<int CTRL>
__device__ __forceinline__ int dpp_i(int v) {
    return __builtin_amdgcn_update_dpp(0, v, CTRL, 0xF, 0xF, true);
}
template<int CTRL>
__device__ __forceinline__ float dpp_f(float v) {
    return __int_as_float(
        __builtin_amdgcn_update_dpp(0, __float_as_int(v), CTRL, 0xF, 0xF, true));
}

__global__ __launch_bounds__(256) __attribute__((amdgpu_waves_per_eu(1, 1)))
void lstm_seq_kernel(
    const float* __restrict__ x,      // (B, T)
    const float* __restrict__ W_ih,   // (60, 1)
    const float* __restrict__ W_hh,   // (60, 15)
    const float* __restrict__ b_ih,   // (60,)
    const float* __restrict__ b_hh,   // (60,)
    const float* __restrict__ W_lin,  // (1, 15)
    const float* __restrict__ b_lin,  // (1,)
    float* __restrict__ out)          // (B, T)
{
    const int tid = threadIdx.x;
    const int sub = tid & 15;                        // lane within 16-row
    const int u   = (sub < HID) ? sub : (HID - 1);   // lane 15 dups unit 14
    const int b   = blockIdx.x * 16 + (tid >> 4);    // batch element

    // ---- self-calibrate the row_ror permutation (direction-proof) ----
    int pos[16];
    pos[0]  = sub;
    pos[1]  = dpp_i<0x121>(sub);  pos[2]  = dpp_i<0x122>(sub);
    pos[3]  = dpp_i<0x123>(sub);  pos[4]  = dpp_i<0x124>(sub);
    pos[5]  = dpp_i<0x125>(sub);  pos[6]  = dpp_i<0x126>(sub);
    pos[7]  = dpp_i<0x127>(sub);  pos[8]  = dpp_i<0x128>(sub);
    pos[9]  = dpp_i<0x129>(sub);  pos[10] = dpp_i<0x12A>(sub);
    pos[11] = dpp_i<0x12B>(sub);  pos[12] = dpp_i<0x12C>(sub);
    pos[13] = dpp_i<0x12D>(sub);  pos[14] = dpp_i<0x12E>(sub);
    pos[15] = dpp_i<0x12F>(sub);

    // ---- packed, pre-rotated weights:
    //      wpA[j] = {W_hh[i-row][p], W_hh[f-row][p]}  (p = pos[j])
    //      wpB[j] = {W_hh[g-row][p], W_hh[o-row][p]}; dup slot (p==15) -> 0
    const int r0 = u, r1 = HID + u, r2 = 2 * HID + u, r3 = 3 * HID + u;
    v2f wpA[16], wpB[16];
#pragma unroll
    for (int j = 0; j < 16; ++j) {
        const int p = pos[j];
        const bool v = (p < HID);
        wpA[j].x = v ? W_hh[r0 * HID + p] : 0.0f;
        wpA[j].y = v ? W_hh[r1 * HID + p] : 0.0f;
        wpB[j].x = v ? W_hh[r2 * HID + p] : 0.0f;
        wpB[j].y = v ? W_hh[r3 * HID + p] : 0.0f;
    }
    v2f wihA; wihA.x = W_ih[r0]; wihA.y = W_ih[r1];
    v2f wihB; wihB.x = W_ih[r2]; wihB.y = W_ih[r3];
    v2f biaA; biaA.x = b_ih[r0] + b_hh[r0]; biaA.y = b_ih[r1] + b_hh[r1];
    v2f biaB; biaB.x = b_ih[r2] + b_hh[r2]; biaB.y = b_ih[r3] + b_hh[r3];
    const float wlin_m = (sub < HID) ? W_lin[sub] : 0.0f;  // lane15 masked
    const float blin = b_lin[0];

    const float L = 1.44269504088896341f;   // log2(e)

    float c = 0.0f, hl = 0.0f;
    float hr[16];
#pragma unroll
    for (int j = 0; j < 16; ++j) hr[j] = 0.0f;

    const float4* __restrict__ x4 = (const float4*)(x + (size_t)b * T_LEN);
    float4* __restrict__ o4       = (float4*)(out + (size_t)b * T_LEN);

    float4 xv = x4[0];
    for (int t0 = 0; t0 < T_LEN / 4; ++t0) {
        const int tn = (t0 + 1 < T_LEN / 4) ? (t0 + 1) : t0;
        const float4 xnext = x4[tn];
        float ov[4];
#pragma unroll
        for (int s = 0; s < 4; ++s) {
            const float xt = (s == 0) ? xv.x : (s == 1) ? xv.y : (s == 2) ? xv.z : xv.w;

            // ---- 2 packed dual-accumulator gate chains (32 pk_fma) ----
            v2f aA0 = biaA; v2f aA1; aA1.x = 0.0f; aA1.y = 0.0f;
            v2f aB0 = biaB; v2f aB1; aB1.x = 0.0f; aB1.y = 0.0f;
#pragma unroll
            for (int j = 0; j < 16; j += 2) {
                v2f h0; h0.x = hr[j];     h0.y = hr[j];
                v2f h1; h1.x = hr[j + 1]; h1.y = hr[j + 1];
                aA0 = fma2(h0, wpA[j],     aA0);
                aB0 = fma2(h0, wpB[j],     aB0);
                aA1 = fma2(h1, wpA[j + 1], aA1);
                aB1 = fma2(h1, wpB[j + 1], aB1);
            }
            v2f xtv; xtv.x = xt; xtv.y = xt;
            const v2f gA = fma2(xtv, wihA, aA0 + aA1);   // {g_i, g_f}
            const v2f gB = fma2(xtv, wihB, aB0 + aB1);   // {g_g, g_o}

            // ---- activations (scalar trans; 4 independent chains) ----
            const float si = __builtin_amdgcn_rcpf(1.0f + __builtin_amdgcn_exp2f(gA.x * -L));
            const float sf = __builtin_amdgcn_rcpf(1.0f + __builtin_amdgcn_exp2f(gA.y * -L));
            const float tg = fmaf(2.0f,
                __builtin_amdgcn_rcpf(1.0f + __builtin_amdgcn_exp2f(gB.x * (-2.0f * L))), -1.0f);
            const float so = __builtin_amdgcn_rcpf(1.0f + __builtin_amdgcn_exp2f(gB.y * -L));

            // ---- lane-local cell update ----
            c = fmaf(sf, c, si * tg);
            const float tc = fmaf(2.0f,
                __builtin_amdgcn_rcpf(1.0f + __builtin_amdgcn_exp2f(c * (-2.0f * L))), -1.0f);
            hl = so * tc;

            // ---- out-projection: DPP butterfly (involutions, off-chain) ----
            float p = hl * wlin_m;
            p += dpp_f<0x0B1>(p);   // quad_perm xor1
            p += dpp_f<0x04E>(p);   // quad_perm xor2
            p += dpp_f<0x140>(p);   // row_mirror   (quad 0<->3, 1<->2)
            p += dpp_f<0x141>(p);   // half_mirror  (quad 0<->1, 2<->3)
            ov[s] = p + blin;

            // ---- h all-gather via 15 independent DPP rotates ----
            hr[0]  = hl;
            hr[1]  = dpp_f<0x121>(hl);  hr[2]  = dpp_f<0x122>(hl);
            hr[3]  = dpp_f<0x123>(hl);  hr[4]  = dpp_f<0x124>(hl);
            hr[5]  = dpp_f<0x125>(hl);  hr[6]  = dpp_f<0x126>(hl);
            hr[7]  = dpp_f<0x127>(hl);  hr[8]  = dpp_f<0x128>(hl);
            hr[9]  = dpp_f<0x129>(hl);  hr[10] = dpp_f<0x12A>(hl);
            hr[11] = dpp_f<0x12B>(hl);  hr[12] = dpp_f<0x12C>(hl);
            hr[13] = dpp_f<0x12D>(hl);  hr[14] = dpp_f<0x12E>(hl);
            hr[15] = dpp_f<0x12F>(hl);
        }
        if (sub == 0) {
            o4[t0] = make_float4(ov[0], ov[1], ov[2], ov[3]);
        }
        xv = xnext;
    }
}

extern "C" void kernel_launch(void* const* d_in, const int* in_sizes, int n_in,
                              void* d_out, int out_size, void* d_ws, size_t ws_size,
                              hipStream_t stream) {
    const float* x     = (const float*)d_in[0];
    const float* W_ih  = (const float*)d_in[1];
    const float* W_hh  = (const float*)d_in[2];
    const float* b_ih  = (const float*)d_in[3];
    const float* b_hh  = (const float*)d_in[4];
    const float* W_lin = (const float*)d_in[5];
    const float* b_lin = (const float*)d_in[6];
    float* out = (float*)d_out;

    dim3 grid(B_TOT / 16);   // 256 blocks of 16 elements
    dim3 block(256);         // 4 waves/block, 4 elements/wave, no LDS/barriers
    lstm_seq_kernel<<<grid, block, 0, stream>>>(x, W_ih, W_hh, b_ih, b_hh,
                                                W_lin, b_lin, out);
}

// Round 9
// 413.814 us; speedup vs baseline: 1.4600x; 1.1016x over previous
//
#include <hip/hip_runtime.h>

// LSTM B=4096, T=2048, H=15.  R8 = R7 with the v2h type fixed (__fp16 to
// match __builtin_amdgcn_cvt_pkrtz / fdot2 signatures).
// 16 lanes per batch element; lane u owns unit u, computes all 4 gates ->
// lane-local cell update, zero LDS, zero barriers. 1024 waves (1/SIMD).
// Gates: v_dot2_f32_f16 (full-rate, 2 FMA/lane/2cy -> 2x f32 FMA rate),
// f32 accumulation, weights pre-scaled by the activation constants:
//   rows i,f,o: x(-log2e); row g: x(-2 log2e)  => exp2(dot) direct.
// State kept as cs = 2*log2e*c so both tanh chains lose their lead mul.
// h gather: pk0={h_u,h_ror1} (1 DPP + 1 cvt_pkrtz), then 7 INDEPENDENT
// packed DPP ror:2k -> 8 f16 pairs; weights pre-rotated via mirrored
// self-calibration (pos[2k]=ror2k(pr0), pos[2k+1]=ror2k(pr1)).

#define HID 15
#define T_LEN 2048
#define B_TOT 4096

typedef __fp16 v2h __attribute__((ext_vector_type(2)));

template<int CTRL>
__device__ __forceinline__ int dpp_i(int v) {
    return __builtin_amdgcn_update_dpp(0, v, CTRL, 0xF, 0xF, true);
}
template<int CTRL>
__device__ __forceinline__ float dpp_f(float v) {
    return __int_as_float(
        __builtin_amdgcn_update_dpp(0, __float_as_int(v), CTRL, 0xF, 0xF, true));
}
template<int CTRL>
__device__ __forceinline__ v2h dpp_h(v2h v) {
    int r = __builtin_amdgcn_update_dpp(0, __builtin_bit_cast(int, v),
                                        CTRL, 0xF, 0xF, true);
    return __builtin_bit_cast(v2h, r);
}

__global__ __launch_bounds__(256) __attribute__((amdgpu_waves_per_eu(1, 1)))
void lstm_seq_kernel(
    const float* __restrict__ x,      // (B, T)
    const float* __restrict__ W_ih,   // (60, 1)
    const float* __restrict__ W_hh,   // (60, 15)
    const float* __restrict__ b_ih,   // (60,)
    const float* __restrict__ b_hh,   // (60,)
    const float* __restrict__ W_lin,  // (1, 15)
    const float* __restrict__ b_lin,  // (1,)
    float* __restrict__ out)          // (B, T)
{
    const int tid = threadIdx.x;
    const int sub = tid & 15;                        // lane within 16-row
    const int u   = (sub < HID) ? sub : (HID - 1);   // lane 15 dups unit 14
    const int b   = blockIdx.x * 16 + (tid >> 4);    // batch element

    // ---- self-calibrate the PAIRED rotation map (mirrors runtime gather) --
    const int pr0 = sub;
    const int pr1 = dpp_i<0x121>(sub);               // ror:1
    int pos[16];
    pos[0]  = pr0;                pos[1]  = pr1;
    pos[2]  = dpp_i<0x122>(pr0);  pos[3]  = dpp_i<0x122>(pr1);
    pos[4]  = dpp_i<0x124>(pr0);  pos[5]  = dpp_i<0x124>(pr1);
    pos[6]  = dpp_i<0x126>(pr0);  pos[7]  = dpp_i<0x126>(pr1);
    pos[8]  = dpp_i<0x128>(pr0);  pos[9]  = dpp_i<0x128>(pr1);
    pos[10] = dpp_i<0x12A>(pr0);  pos[11] = dpp_i<0x12A>(pr1);
    pos[12] = dpp_i<0x12C>(pr0);  pos[13] = dpp_i<0x12C>(pr1);
    pos[14] = dpp_i<0x12E>(pr0);  pos[15] = dpp_i<0x12E>(pr1);

    // ---- f16 weights, pre-rotated + pre-scaled by activation constants ----
    const double Ld = 1.4426950408889634074;         // log2(e)
    const float  SI = (float)(-Ld);                  // rows i, f, o
    const float  SG = (float)(-2.0 * Ld);            // row g
    const int r0 = u, r1 = HID + u, r2 = 2 * HID + u, r3 = 3 * HID + u;
    v2h wi[8], wf[8], wg[8], wo[8];
#pragma unroll
    for (int j = 0; j < 8; ++j) {
        const int p0 = pos[2 * j], p1 = pos[2 * j + 1];
        const bool v0 = (p0 < HID), v1 = (p1 < HID);
        wi[j].x = (__fp16)(v0 ? W_hh[r0 * HID + p0] * SI : 0.0f);
        wi[j].y = (__fp16)(v1 ? W_hh[r0 * HID + p1] * SI : 0.0f);
        wf[j].x = (__fp16)(v0 ? W_hh[r1 * HID + p0] * SI : 0.0f);
        wf[j].y = (__fp16)(v1 ? W_hh[r1 * HID + p1] * SI : 0.0f);
        wg[j].x = (__fp16)(v0 ? W_hh[r2 * HID + p0] * SG : 0.0f);
        wg[j].y = (__fp16)(v1 ? W_hh[r2 * HID + p1] * SG : 0.0f);
        wo[j].x = (__fp16)(v0 ? W_hh[r3 * HID + p0] * SI : 0.0f);
        wo[j].y = (__fp16)(v1 ? W_hh[r3 * HID + p1] * SI : 0.0f);
    }
    const float wih_i = W_ih[r0] * SI, wih_f = W_ih[r1] * SI;
    const float wih_g = W_ih[r2] * SG, wih_o = W_ih[r3] * SI;
    const float bia_i = (b_ih[r0] + b_hh[r0]) * SI;
    const float bia_f = (b_ih[r1] + b_hh[r1]) * SI;
    const float bia_g = (b_ih[r2] + b_hh[r2]) * SG;
    const float bia_o = (b_ih[r3] + b_hh[r3]) * SI;
    const float wlin_m = (sub < HID) ? W_lin[sub] : 0.0f;   // lane15 masked
    const float blin = b_lin[0];
    const float C4L  = (float)(4.0 * Ld);            // for tg2 = 2L*tanh(g)
    const float CN2L = (float)(-2.0 * Ld);

    float cs = 0.0f;    // cs = 2*log2e * c   (scaled cell state)
    float hl = 0.0f;    // h for this lane's unit (f32)

    const float4* __restrict__ x4 = (const float4*)(x + (size_t)b * T_LEN);
    float4* __restrict__ o4       = (float4*)(out + (size_t)b * T_LEN);

    float4 xv = x4[0];
    for (int t0 = 0; t0 < T_LEN / 4; ++t0) {
        const int tn = (t0 + 1 < T_LEN / 4) ? (t0 + 1) : t0;
        const float4 xnext = x4[tn];                 // prefetch
        float ov[4];
#pragma unroll
        for (int s = 0; s < 4; ++s) {
            const float xt = (s == 0) ? xv.x : (s == 1) ? xv.y : (s == 2) ? xv.z : xv.w;

            // ---- packed h gather: 1 DPP + 1 cvt_pkrtz + 7 indep DPP ----
            const float h1 = dpp_f<0x121>(hl);       // ror:1 neighbor
            v2h pk[8];
            pk[0] = __builtin_amdgcn_cvt_pkrtz(hl, h1);
            pk[1] = dpp_h<0x122>(pk[0]);
            pk[2] = dpp_h<0x124>(pk[0]);
            pk[3] = dpp_h<0x126>(pk[0]);
            pk[4] = dpp_h<0x128>(pk[0]);
            pk[5] = dpp_h<0x12A>(pk[0]);
            pk[6] = dpp_h<0x12C>(pk[0]);
            pk[7] = dpp_h<0x12E>(pk[0]);

            // ---- 4 gate rows via full-rate f16 dot2, f32 accumulate ----
            float ai = bia_i, af = bia_f, ag = bia_g, aq = bia_o;
#pragma unroll
            for (int j = 0; j < 8; ++j) {
                ai = __builtin_amdgcn_fdot2(pk[j], wi[j], ai, false);
                af = __builtin_amdgcn_fdot2(pk[j], wf[j], af, false);
                ag = __builtin_amdgcn_fdot2(pk[j], wg[j], ag, false);
                aq = __builtin_amdgcn_fdot2(pk[j], wo[j], aq, false);
            }
            const float gi = fmaf(xt, wih_i, ai);    // = -L  * raw_i
            const float gf = fmaf(xt, wih_f, af);    // = -L  * raw_f
            const float gg = fmaf(xt, wih_g, ag);    // = -2L * raw_g
            const float go = fmaf(xt, wih_o, aq);    // = -L  * raw_o

            // ---- activations: args pre-scaled, exp2 direct ----
            const float si = __builtin_amdgcn_rcpf(1.0f + __builtin_amdgcn_exp2f(gi));
            const float sf = __builtin_amdgcn_rcpf(1.0f + __builtin_amdgcn_exp2f(gf));
            const float rg = __builtin_amdgcn_rcpf(1.0f + __builtin_amdgcn_exp2f(gg));
            const float so = __builtin_amdgcn_rcpf(1.0f + __builtin_amdgcn_exp2f(go));
            const float tg2 = fmaf(C4L, rg, CN2L);   // = 2L * tanh(raw_g)

            // ---- scaled cell update: cs = sf*cs + si*tg2  (= 2L*c_new) ----
            cs = fmaf(sf, cs, si * tg2);
            const float rc = __builtin_amdgcn_rcpf(1.0f + __builtin_amdgcn_exp2f(-cs));
            const float tso = so + so;               // off-chain
            hl = fmaf(tso, rc, -so);                 // = so * tanh(c_new)

            // ---- out-projection: DPP butterfly (involutions, off-chain) ----
            float p = hl * wlin_m;
            p += dpp_f<0x0B1>(p);   // quad_perm xor1
            p += dpp_f<0x04E>(p);   // quad_perm xor2
            p += dpp_f<0x140>(p);   // row_mirror
            p += dpp_f<0x141>(p);   // half_mirror
            ov[s] = p + blin;
        }
        if (sub == 0) {
            o4[t0] = make_float4(ov[0], ov[1], ov[2], ov[3]);
        }
        xv = xnext;
    }
}

extern "C" void kernel_launch(void* const* d_in, const int* in_sizes, int n_in,
                              void* d_out, int out_size, void* d_ws, size_t ws_size,
                              hipStream_t stream) {
    const float* x     = (const float*)d_in[0];
    const float* W_ih  = (const float*)d_in[1];
    const float* W_hh  = (const float*)d_in[2];
    const float* b_ih  = (const float*)d_in[3];
    const float* b_hh  = (const float*)d_in[4];
    const float* W_lin = (const float*)d_in[5];
    const float* b_lin = (const float*)d_in[6];
    float* out = (float*)d_out;

    dim3 grid(B_TOT / 16);   // 256 blocks of 16 elements
    dim3 block(256);         // 4 waves/block, 4 elements/wave
    lstm_seq_kernel<<<grid, block, 0, stream>>>(x, W_ih, W_hh, b_ih, b_hh,
                                                W_lin, b_lin, out);
}